// Round 8
// baseline (136.958 us; speedup 1.0000x reference)
//
#include <hip/hip_runtime.h>
#include <math.h>

#define E_TOTAL  200000
#define NNODES   12500
#define OUT_ELEM 800000          // 12500 * 64
#define NTILE    (E_TOTAL / 64)  // 3125
#define PAD      64              // max tracked degree (Poisson(16): P(>64) ~ 1e-20)

typedef float    f32x4 __attribute__((ext_vector_type(4)));
typedef _Float16 f16x8 __attribute__((ext_vector_type(8)));
typedef _Float16 f16x4 __attribute__((ext_vector_type(4)));
typedef _Float16 f16x2 __attribute__((ext_vector_type(2)));

union AF { f16x8 f; f16x2 h2[4]; };

// ---------------- workspace layout (bytes), ws_size ~256 MiB ----------------
// edge_pad : f16  NNODES*PAD*64  (per-node padded rows, alpha folded in)
// cnt      : int  NNODES
// bfrag    : f16  36*64*8        (alpha-scaled, MFMA B-layout)
static const size_t OFF_CNT    = (size_t)NNODES * PAD * 64 * 2;         // 102,400,000
static const size_t OFF_BFRAG  = (OFF_CNT + (size_t)NNODES * 4 + 15) & ~(size_t)15;
static const size_t WS_NEEDED  = OFF_BFRAG + (size_t)36 * 64 * 8 * 2;

// ================= prep: cnt=0 + swizzled f16 B-fragments =================
// B-frag layout for mfma_f32_16x16x32_f16: lane holds B[k=quad*8+j][n=lane&15].
// slot = br*9+kb; kb<8: ku = kb*32+quad*8+j -> w2[ku>>4][br*256+(ku&15)*16+n]
//                 kb==8: bias block (loc<16 -> b2, else 0). alpha folded in.
__global__ void k_prep(const float* __restrict__ w2, const float* __restrict__ b2,
                       int* __restrict__ cnt, _Float16* __restrict__ bfrag) {
    const int g = blockIdx.x * 256 + threadIdx.x;
    if (g < NNODES) cnt[g] = 0;
    if (g < 36 * 64) {
        const int slot = g >> 6, lane = g & 63;
        const int br = slot / 9, kb = slot - br * 9;
        const int quad = lane >> 4, n = lane & 15;
        const float alpha = 0.17677669529663687f;   // 1/sqrt(32)
        _Float16* dst = bfrag + (size_t)g * 8;
        #pragma unroll
        for (int j = 0; j < 8; ++j) {
            float v;
            if (kb < 8) {
                const int ku = kb * 32 + quad * 8 + j;
                v = w2[(ku >> 4) * 1024 + br * 256 + (ku & 15) * 16 + n];
            } else {
                const int loc = quad * 8 + j;
                v = (loc < 16) ? b2[br * 256 + loc * 16 + n] : 0.0f;
            }
            dst[j] = (_Float16)(alpha * v);
        }
    }
}

// ================= fused conv (f16 MFMA) + slot claim =================
// Block = 4 waves, 64 edges (blockIdx = tile). Per wave 16 edges; six GEMMs
// C(16e x 16w) = A(16 x 288) @ B(288 x 16); kb=8 is the bias block. A rank-1:
//   A[m][quad*8+j] = h[m][2kb+(quad>>1)] * s[m][(quad&1)*8+j]
// C/D: row(edge) = quad*4+reg, col(w) = lane&15. alpha folded into B.
// Threads t<64 claim a per-dst slot; epilogue scatters the 128 B row there.
__global__ __launch_bounds__(256) void k_conv(
        const float* __restrict__ node_attr,
        const int*   __restrict__ edge_index,
        const float* __restrict__ edge_attr,
        const float* __restrict__ edge_sh,
        const float* __restrict__ w1,
        const float* __restrict__ b1,
        const f16x8* __restrict__ bfrag,
        int* __restrict__ cnt,
        _Float16* __restrict__ edge_pad)
{
    const int t = threadIdx.x;
    __shared__ float  sh_h[64][17];                 // 4352 B
    __shared__ float4 sh_y[64];                     // 1024 B
    __shared__ _Float16 sh_s[6][64][24];            // 18432 B (48 B rows)
    __shared__ int    sh_row[64];                   //  256 B  -> 24064 B total

    const int ebase = blockIdx.x * 64;
    const float inv_sqrt3 = 0.57735026918962576f;

    // ---- slot claim for this block's 64 edges (one atomic per edge)
    if (t < 64) {
        const int e2 = ebase + t;
        const int d = edge_index[E_TOTAL + e2];
        int slot = atomicAdd(&cnt[d], 1);
        if (slot >= PAD) slot = PAD - 1;            // memory-safety clamp (never hit)
        sh_row[t] = d * PAD + slot;
    }

    // ---- phase 1a: h = silu(edge_attr @ w1 + b1)
    {
        const int e_loc = t & 63, kq = t >> 6;
        const int e = ebase + e_loc;
        const float* ea = edge_attr + (size_t)e * 16;
        float ear[16];
        #pragma unroll
        for (int dq = 0; dq < 4; ++dq) {
            float4 v = *(const float4*)(ea + dq * 4);
            ear[dq * 4 + 0] = v.x; ear[dq * 4 + 1] = v.y;
            ear[dq * 4 + 2] = v.z; ear[dq * 4 + 3] = v.w;
        }
        float4 acc = *(const float4*)(b1 + kq * 4);
        #pragma unroll
        for (int d = 0; d < 16; ++d) {
            float4 wr = *(const float4*)(w1 + d * 16 + kq * 4);
            acc.x += ear[d] * wr.x; acc.y += ear[d] * wr.y;
            acc.z += ear[d] * wr.z; acc.w += ear[d] * wr.w;
        }
        sh_h[e_loc][kq * 4 + 0] = acc.x / (1.0f + __expf(-acc.x));
        sh_h[e_loc][kq * 4 + 1] = acc.y / (1.0f + __expf(-acc.y));
        sh_h[e_loc][kq * 4 + 2] = acc.z / (1.0f + __expf(-acc.z));
        sh_h[e_loc][kq * 4 + 3] = acc.w / (1.0f + __expf(-acc.w));
    }

    // ---- phase 1b: stage s-vectors (f16) + y
    {
        const int e_loc = (t & 15) + ((t >> 6) << 4);
        const int pp = (t >> 4) & 3;
        const int u0 = pp * 4;
        const int e = ebase + e_loc;
        const int src = edge_index[e];
        const float4 yv = *(const float4*)(edge_sh + (size_t)e * 4);
        const float* xp = node_attr + (size_t)src * 64;
        float4 x0v = *(const float4*)(xp + u0);
        float x1v[4][3];
        #pragma unroll
        for (int q = 0; q < 4; ++q)
            #pragma unroll
            for (int i = 0; i < 3; ++i)
                x1v[q][i] = xp[16 + (u0 + q) * 3 + i];
        const float* x0p = &x0v.x;
        f16x4 s0h, s1h, x0h, ah, bh, ch;
        #pragma unroll
        for (int q = 0; q < 4; ++q) {
            s0h[q] = (_Float16)(x0p[q] * yv.x);
            s1h[q] = (_Float16)(inv_sqrt3 * (x1v[q][0] * yv.y + x1v[q][1] * yv.z + x1v[q][2] * yv.w));
            x0h[q] = (_Float16)x0p[q];
            ah[q]  = (_Float16)x1v[q][0];
            bh[q]  = (_Float16)x1v[q][1];
            ch[q]  = (_Float16)x1v[q][2];
        }
        *(f16x4*)&sh_s[0][e_loc][u0] = s0h;
        *(f16x4*)&sh_s[1][e_loc][u0] = s1h;
        *(f16x4*)&sh_s[2][e_loc][u0] = x0h;
        *(f16x4*)&sh_s[3][e_loc][u0] = ah;
        *(f16x4*)&sh_s[4][e_loc][u0] = bh;
        *(f16x4*)&sh_s[5][e_loc][u0] = ch;
        if (pp == 0) sh_y[e_loc] = yv;
    }
    __syncthreads();

    // ---- phase 2: MFMA K-loop
    const int lane = t & 63, wv = t >> 6;
    const int m = lane & 15, quad = lane >> 4;
    const int e_loc = wv * 16 + m;
    const int qh = quad >> 1, ql = quad & 1;

    AF svh[6];
    #pragma unroll
    for (int b = 0; b < 6; ++b)
        svh[b].f = *(const f16x8*)&sh_s[b][e_loc][ql * 8];
    float hreg[8];
    #pragma unroll
    for (int kb = 0; kb < 8; ++kb) hreg[kb] = sh_h[e_loc][2 * kb + qh];

    f32x4 acc0  = {0.f, 0.f, 0.f, 0.f};
    f32x4 acc2  = {0.f, 0.f, 0.f, 0.f};
    f32x4 acc3a = {0.f, 0.f, 0.f, 0.f};
    f32x4 acc3b = {0.f, 0.f, 0.f, 0.f};
    f32x4 acc3c = {0.f, 0.f, 0.f, 0.f};

    for (int kb = 0; kb < 9; ++kb) {
        const f16x8 B0 = bfrag[(0 * 9 + kb) * 64 + lane];
        const f16x8 B1 = bfrag[(1 * 9 + kb) * 64 + lane];
        const f16x8 B2 = bfrag[(2 * 9 + kb) * 64 + lane];
        const f16x8 B3 = bfrag[(3 * 9 + kb) * 64 + lane];
        const float selF = (kb < 8) ? hreg[kb] : ((quad < 2) ? 1.0f : 0.0f);
        const _Float16 sh1 = (_Float16)selF;
        const f16x2 sel2 = (f16x2){sh1, sh1};
        AF A[6];
        #pragma unroll
        for (int b = 0; b < 6; ++b)
            #pragma unroll
            for (int p = 0; p < 4; ++p)
                A[b].h2[p] = sel2 * svh[b].h2[p];    // v_pk_mul_f16
        acc0  = __builtin_amdgcn_mfma_f32_16x16x32_f16(A[0].f, B0, acc0, 0, 0, 0);
        acc0  = __builtin_amdgcn_mfma_f32_16x16x32_f16(A[1].f, B1, acc0, 0, 0, 0);
        acc2  = __builtin_amdgcn_mfma_f32_16x16x32_f16(A[2].f, B2, acc2, 0, 0, 0);
        acc3a = __builtin_amdgcn_mfma_f32_16x16x32_f16(A[3].f, B3, acc3a, 0, 0, 0);
        acc3b = __builtin_amdgcn_mfma_f32_16x16x32_f16(A[4].f, B3, acc3b, 0, 0, 0);
        acc3c = __builtin_amdgcn_mfma_f32_16x16x32_f16(A[5].f, B3, acc3c, 0, 0, 0);
    }

    // ---- epilogue: scatter f16 lane-chunked rows to claimed slots
    #pragma unroll
    for (int r = 0; r < 4; ++r) {
        const int el = wv * 16 + quad * 4 + r;
        const float4 yv = sh_y[el];
        const float t2v = acc2[r];
        const float o0 = acc0[r];
        const float oa = yv.y * t2v + yv.x * acc3a[r];
        const float ob = yv.z * t2v + yv.x * acc3b[r];
        const float oc = yv.w * t2v + yv.x * acc3c[r];
        f16x4 pk = {(_Float16)o0, (_Float16)oa, (_Float16)ob, (_Float16)oc};
        const int row = sh_row[el];
        *(f16x4*)(edge_pad + (size_t)row * 64 + m * 4) = pk;
    }
}

// ================= gather (segment mean): dense streaming read =================
// One wave per node (12500 = 3125 blocks * 4 waves). Node n's rows are
// contiguous at edge_pad + n*PAD*64 — independent loads, no pointer chase.
__global__ __launch_bounds__(256) void k_gather(const _Float16* __restrict__ edge_pad,
                                                const int* __restrict__ cnt,
                                                float* __restrict__ out) {
    const int t = threadIdx.x;
    const int lane = t & 63;
    const int n = blockIdx.x * 4 + (t >> 6);
    // in-row permutation: elem<16 -> row[elem*4]; elem=16+w*3+i -> row[w*4+1+i]
    int pe;
    if (lane < 16) pe = lane * 4;
    else { const int idx = lane - 16; const int w = idx / 3; pe = w * 4 + 1 + (idx - w * 3); }
    int c = cnt[n];
    if (c > PAD) c = PAD;
    const _Float16* base = edge_pad + (size_t)n * PAD * 64 + pe;
    float a0 = 0.0f, a1 = 0.0f;
    int j = 0;
    for (; j + 2 <= c; j += 2) {            // 2-way MLP unroll
        a0 += (float)base[(size_t)j * 64];
        a1 += (float)base[(size_t)(j + 1) * 64];
    }
    if (j < c) a0 += (float)base[(size_t)j * 64];
    const float acc = a0 + a1;
    out[n * 64 + lane] = acc / (c > 0 ? (float)c : 1.0f);
}

// ================= fallback path (round-1 atomic fp32, proven) =================
__global__ void k_zero_f(float* __restrict__ out, float* __restrict__ counts) {
    int i = blockIdx.x * 256 + threadIdx.x;
    if (i < OUT_ELEM) out[i] = 0.0f;
    if (i < NNODES)   counts[i] = 0.0f;
}

#define EPB 80
#define NE  8
__global__ __launch_bounds__(256) void k_conv_atomic(
        const float* __restrict__ node_attr,
        const int*   __restrict__ edge_index,
        const float* __restrict__ edge_attr,
        const float* __restrict__ edge_sh,
        const float* __restrict__ w1,
        const float* __restrict__ b1,
        const float* __restrict__ w2,
        const float* __restrict__ b2,
        float* __restrict__ out,
        float* __restrict__ counts)
{
    const int thr   = threadIdx.x;
    const int lane  = thr & 63;
    const int wv    = thr >> 6;
    const int u     = lane >> 2;
    const int wbase = (lane & 3) * 4;

    float4 w2r[16];
    #pragma unroll
    for (int k = 0; k < 16; ++k)
        w2r[k] = *(const float4*)(w2 + k * 1024 + thr * 4);
    const float4 b2r = *(const float4*)(b2 + thr * 4);

    __shared__ __align__(16) float sh_h[NE][16];
    __shared__ float sh_s0[NE][16];
    __shared__ float sh_s1[NE][16];
    __shared__ float sh_x0[NE][16];
    __shared__ float sh_x1[NE][16][3];
    __shared__ float sh_y0[NE];
    __shared__ float sh_y1[NE][3];
    __shared__ int   sh_dst[NE];

    const float alpha     = 0.17677669529663687f;
    const float inv_sqrt3 = 0.57735026918962576f;
    const int e0 = blockIdx.x * EPB;

    for (int batch = 0; batch < EPB / NE; ++batch) {
        const int ebase = e0 + batch * NE;
        if (thr < 128) {
            const int le = thr >> 4, k = thr & 15;
            const int e = ebase + le;
            float acc = b1[k];
            const float* ea = edge_attr + (size_t)e * 16;
            #pragma unroll
            for (int d = 0; d < 16; ++d) acc += ea[d] * w1[d * 16 + k];
            sh_h[le][k] = acc / (1.0f + __expf(-acc));
            if (k == 0) sh_dst[le] = edge_index[E_TOTAL + e];
        } else {
            const int le = (thr - 128) >> 4, uu = thr & 15;
            const int e = ebase + le;
            const int src = edge_index[e];
            const float y0  = edge_sh[e * 4 + 0];
            const float y1a = edge_sh[e * 4 + 1];
            const float y1b = edge_sh[e * 4 + 2];
            const float y1c = edge_sh[e * 4 + 3];
            const float* xp = node_attr + (size_t)src * 64;
            const float x0v = xp[uu];
            const float xa = xp[16 + uu * 3 + 0];
            const float xb = xp[16 + uu * 3 + 1];
            const float xc = xp[16 + uu * 3 + 2];
            sh_x0[le][uu] = x0v;
            sh_x1[le][uu][0] = xa; sh_x1[le][uu][1] = xb; sh_x1[le][uu][2] = xc;
            sh_s0[le][uu] = x0v * y0;
            sh_s1[le][uu] = inv_sqrt3 * (xa * y1a + xb * y1b + xc * y1c);
            if (uu == 0) {
                sh_y0[le] = y0;
                sh_y1[le][0] = y1a; sh_y1[le][1] = y1b; sh_y1[le][2] = y1c;
            }
        }
        __syncthreads();

        for (int le = 0; le < NE; ++le) {
            float W0 = b2r.x, W1 = b2r.y, W2c = b2r.z, W3c = b2r.w;
            const float4* hv = (const float4*)sh_h[le];
            #pragma unroll
            for (int kk = 0; kk < 4; ++kk) {
                const float4 h4 = hv[kk];
                const int kb = kk * 4;
                W0  += h4.x * w2r[kb + 0].x; W1  += h4.x * w2r[kb + 0].y;
                W2c += h4.x * w2r[kb + 0].z; W3c += h4.x * w2r[kb + 0].w;
                W0  += h4.y * w2r[kb + 1].x; W1  += h4.y * w2r[kb + 1].y;
                W2c += h4.y * w2r[kb + 1].z; W3c += h4.y * w2r[kb + 1].w;
                W0  += h4.z * w2r[kb + 2].x; W1  += h4.z * w2r[kb + 2].y;
                W2c += h4.z * w2r[kb + 2].z; W3c += h4.z * w2r[kb + 2].w;
                W0  += h4.w * w2r[kb + 3].x; W1  += h4.w * w2r[kb + 3].y;
                W2c += h4.w * w2r[kb + 3].z; W3c += h4.w * w2r[kb + 3].w;
            }
            const int dst = sh_dst[le];
            float* op = out + (size_t)dst * 64;
            if (wv == 0 || wv == 1) {
                const float s = (wv == 0) ? sh_s0[le][u] : sh_s1[le][u];
                float v0 = s * W0, v1 = s * W1, v2 = s * W2c, v3 = s * W3c;
                #pragma unroll
                for (int off = 4; off <= 32; off <<= 1) {
                    v0 += __shfl_xor(v0, off); v1 += __shfl_xor(v1, off);
                    v2 += __shfl_xor(v2, off); v3 += __shfl_xor(v3, off);
                }
                if (lane < 4) {
                    atomicAdd(op + wbase + 0, alpha * v0);
                    atomicAdd(op + wbase + 1, alpha * v1);
                    atomicAdd(op + wbase + 2, alpha * v2);
                    atomicAdd(op + wbase + 3, alpha * v3);
                    if (wv == 0 && lane == 0) atomicAdd(&counts[dst], 1.0f);
                }
            } else if (wv == 2) {
                const float s = sh_x0[le][u];
                float v0 = s * W0, v1 = s * W1, v2 = s * W2c, v3 = s * W3c;
                #pragma unroll
                for (int off = 4; off <= 32; off <<= 1) {
                    v0 += __shfl_xor(v0, off); v1 += __shfl_xor(v1, off);
                    v2 += __shfl_xor(v2, off); v3 += __shfl_xor(v3, off);
                }
                if (lane < 4) {
                    const float ya = alpha * sh_y1[le][0];
                    const float yb = alpha * sh_y1[le][1];
                    const float yc = alpha * sh_y1[le][2];
                    float vv[4] = {v0, v1, v2, v3};
                    #pragma unroll
                    for (int q = 0; q < 4; ++q) {
                        float* qp = op + 16 + (wbase + q) * 3;
                        atomicAdd(qp + 0, vv[q] * ya);
                        atomicAdd(qp + 1, vv[q] * yb);
                        atomicAdd(qp + 2, vv[q] * yc);
                    }
                }
            } else {
                const float ay0 = alpha * sh_y0[le];
                #pragma unroll
                for (int i = 0; i < 3; ++i) {
                    const float s = sh_x1[le][u][i];
                    float v0 = s * W0, v1 = s * W1, v2 = s * W2c, v3 = s * W3c;
                    #pragma unroll
                    for (int off = 4; off <= 32; off <<= 1) {
                        v0 += __shfl_xor(v0, off); v1 += __shfl_xor(v1, off);
                        v2 += __shfl_xor(v2, off); v3 += __shfl_xor(v3, off);
                    }
                    if (lane < 4) {
                        atomicAdd(op + 16 + (wbase + 0) * 3 + i, ay0 * v0);
                        atomicAdd(op + 16 + (wbase + 1) * 3 + i, ay0 * v1);
                        atomicAdd(op + 16 + (wbase + 2) * 3 + i, ay0 * v2);
                        atomicAdd(op + 16 + (wbase + 3) * 3 + i, ay0 * v3);
                    }
                }
            }
        }
        __syncthreads();
    }
}

__global__ void k_div(float* __restrict__ out, const float* __restrict__ counts) {
    int i = blockIdx.x * 256 + threadIdx.x;
    if (i < OUT_ELEM) {
        float c = counts[i >> 6];
        out[i] *= 1.0f / fmaxf(c, 1.0f);
    }
}

// ================= launch =================
extern "C" void kernel_launch(void* const* d_in, const int* in_sizes, int n_in,
                              void* d_out, int out_size, void* d_ws, size_t ws_size,
                              hipStream_t stream) {
    const float* node_attr  = (const float*)d_in[0];
    const int*   edge_index = (const int*)d_in[1];
    const float* edge_attr  = (const float*)d_in[2];
    const float* edge_sh    = (const float*)d_in[3];
    const float* w1         = (const float*)d_in[4];
    const float* b1         = (const float*)d_in[5];
    const float* w2         = (const float*)d_in[6];
    const float* b2         = (const float*)d_in[7];
    float* out = (float*)d_out;

    if (ws_size >= WS_NEEDED) {
        char* ws = (char*)d_ws;
        _Float16* edge_pad = (_Float16*)ws;
        int*      cnt      = (int*)(ws + OFF_CNT);
        _Float16* bfrag    = (_Float16*)(ws + OFF_BFRAG);

        k_prep<<<(NNODES + 255) / 256, 256, 0, stream>>>(w2, b2, cnt, bfrag);
        k_conv<<<NTILE, 256, 0, stream>>>(
            node_attr, edge_index, edge_attr, edge_sh, w1, b1,
            (const f16x8*)bfrag, cnt, edge_pad);
        k_gather<<<NNODES / 4, 256, 0, stream>>>(edge_pad, cnt, out);
    } else {
        float* counts = (float*)d_ws;
        k_zero_f<<<(OUT_ELEM + 255) / 256, 256, 0, stream>>>(out, counts);
        k_conv_atomic<<<E_TOTAL / EPB, 256, 0, stream>>>(
            node_attr, edge_index, edge_attr, edge_sh, w1, b1, w2, b2, out, counts);
        k_div<<<(OUT_ELEM + 255) / 256, 256, 0, stream>>>(out, counts);
    }
}

// Round 9
// 123.314 us; speedup vs baseline: 1.1106x; 1.1106x over previous
//
#include <hip/hip_runtime.h>
#include <math.h>

#define E_TOTAL  200000
#define NNODES   12500
#define OUT_ELEM 800000          // 12500 * 64
#define NTILE    (E_TOTAL / 64)  // 3125
#define PAD      64              // max tracked degree (Poisson(16): P(>64) ~ 1e-20)

typedef float    f32x4 __attribute__((ext_vector_type(4)));
typedef _Float16 f16x8 __attribute__((ext_vector_type(8)));
typedef _Float16 f16x4 __attribute__((ext_vector_type(4)));
typedef _Float16 f16x2 __attribute__((ext_vector_type(2)));

union AF { f16x8 f; f16x2 h2[4]; };

// ---------------- workspace layout (bytes) ----------------
// edge_out : f16  E*64        (contiguous per-edge rows, alpha folded in)
// cnt      : int  NNODES
// pos      : int  NNODES*PAD  (slot map: node -> its edge ids)
// bfrag    : f16  36*64*8     (alpha-scaled, MFMA B-layout)
static const size_t OFF_CNT    = (size_t)E_TOTAL * 64 * 2;              // 25,600,000
static const size_t OFF_POS    = OFF_CNT + (size_t)NNODES * 4;
static const size_t OFF_BFRAG  = (OFF_POS + (size_t)NNODES * PAD * 4 + 15) & ~(size_t)15;
static const size_t WS_NEEDED  = OFF_BFRAG + (size_t)36 * 64 * 8 * 2;

// ================= prep: cnt=0 + swizzled f16 B-fragments =================
// B-frag layout for mfma_f32_16x16x32_f16: lane holds B[k=quad*8+j][n=lane&15].
// slot = br*9+kb; kb<8: ku = kb*32+quad*8+j -> w2[ku>>4][br*256+(ku&15)*16+n]
//                 kb==8: bias block (loc<16 -> b2, else 0). alpha folded in.
__global__ void k_prep(const float* __restrict__ w2, const float* __restrict__ b2,
                       int* __restrict__ cnt, _Float16* __restrict__ bfrag) {
    const int g = blockIdx.x * 256 + threadIdx.x;
    if (g < NNODES) cnt[g] = 0;
    if (g < 36 * 64) {
        const int slot = g >> 6, lane = g & 63;
        const int br = slot / 9, kb = slot - br * 9;
        const int quad = lane >> 4, n = lane & 15;
        const float alpha = 0.17677669529663687f;   // 1/sqrt(32)
        _Float16* dst = bfrag + (size_t)g * 8;
        #pragma unroll
        for (int j = 0; j < 8; ++j) {
            float v;
            if (kb < 8) {
                const int ku = kb * 32 + quad * 8 + j;
                v = w2[(ku >> 4) * 1024 + br * 256 + (ku & 15) * 16 + n];
            } else {
                const int loc = quad * 8 + j;
                v = (loc < 16) ? b2[br * 256 + loc * 16 + n] : 0.0f;
            }
            dst[j] = (_Float16)(alpha * v);
        }
    }
}

// ================= fused conv (f16 MFMA) + slot-map build =================
// Block = 4 waves, 64 edges (blockIdx = tile). Per wave 16 edges; six GEMMs
// C(16e x 16w) = A(16 x 288) @ B(288 x 16); kb=8 is the bias block. A rank-1:
//   A[m][quad*8+j] = h[m][2kb+(quad>>1)] * s[m][(quad&1)*8+j]
// C/D: row(edge) = quad*4+reg, col(w) = lane&15. alpha folded into B.
// Stores are CONTIGUOUS per edge (2 KB/wave); only the 4 B slot-map entry
// scatters (32x less scattered traffic than scattering the rows).
__global__ __launch_bounds__(256) void k_conv(
        const float* __restrict__ node_attr,
        const int*   __restrict__ edge_index,
        const float* __restrict__ edge_attr,
        const float* __restrict__ edge_sh,
        const float* __restrict__ w1,
        const float* __restrict__ b1,
        const f16x8* __restrict__ bfrag,
        int* __restrict__ cnt,
        int* __restrict__ pos,
        _Float16* __restrict__ edge_out)
{
    const int t = threadIdx.x;
    __shared__ float  sh_h[64][17];                 // 4352 B
    __shared__ float4 sh_y[64];                     // 1024 B
    __shared__ _Float16 sh_s[6][64][24];            // 18432 B (48 B rows)

    const int ebase = blockIdx.x * 64;
    const float inv_sqrt3 = 0.57735026918962576f;

    // ---- slot-map insert for this block's 64 edges (4 B scattered stores)
    if (t < 64) {
        const int e2 = ebase + t;
        const int d = edge_index[E_TOTAL + e2];
        int slot = atomicAdd(&cnt[d], 1);
        if (slot >= PAD) slot = PAD - 1;            // memory-safety clamp (never hit)
        pos[d * PAD + slot] = e2;
    }

    // ---- phase 1a: h = silu(edge_attr @ w1 + b1)
    {
        const int e_loc = t & 63, kq = t >> 6;
        const int e = ebase + e_loc;
        const float* ea = edge_attr + (size_t)e * 16;
        float ear[16];
        #pragma unroll
        for (int dq = 0; dq < 4; ++dq) {
            float4 v = *(const float4*)(ea + dq * 4);
            ear[dq * 4 + 0] = v.x; ear[dq * 4 + 1] = v.y;
            ear[dq * 4 + 2] = v.z; ear[dq * 4 + 3] = v.w;
        }
        float4 acc = *(const float4*)(b1 + kq * 4);
        #pragma unroll
        for (int d = 0; d < 16; ++d) {
            float4 wr = *(const float4*)(w1 + d * 16 + kq * 4);
            acc.x += ear[d] * wr.x; acc.y += ear[d] * wr.y;
            acc.z += ear[d] * wr.z; acc.w += ear[d] * wr.w;
        }
        sh_h[e_loc][kq * 4 + 0] = acc.x / (1.0f + __expf(-acc.x));
        sh_h[e_loc][kq * 4 + 1] = acc.y / (1.0f + __expf(-acc.y));
        sh_h[e_loc][kq * 4 + 2] = acc.z / (1.0f + __expf(-acc.z));
        sh_h[e_loc][kq * 4 + 3] = acc.w / (1.0f + __expf(-acc.w));
    }

    // ---- phase 1b: stage s-vectors (f16) + y
    {
        const int e_loc = (t & 15) + ((t >> 6) << 4);
        const int pp = (t >> 4) & 3;
        const int u0 = pp * 4;
        const int e = ebase + e_loc;
        const int src = edge_index[e];
        const float4 yv = *(const float4*)(edge_sh + (size_t)e * 4);
        const float* xp = node_attr + (size_t)src * 64;
        float4 x0v = *(const float4*)(xp + u0);
        float x1v[4][3];
        #pragma unroll
        for (int q = 0; q < 4; ++q)
            #pragma unroll
            for (int i = 0; i < 3; ++i)
                x1v[q][i] = xp[16 + (u0 + q) * 3 + i];
        const float* x0p = &x0v.x;
        f16x4 s0h, s1h, x0h, ah, bh, ch;
        #pragma unroll
        for (int q = 0; q < 4; ++q) {
            s0h[q] = (_Float16)(x0p[q] * yv.x);
            s1h[q] = (_Float16)(inv_sqrt3 * (x1v[q][0] * yv.y + x1v[q][1] * yv.z + x1v[q][2] * yv.w));
            x0h[q] = (_Float16)x0p[q];
            ah[q]  = (_Float16)x1v[q][0];
            bh[q]  = (_Float16)x1v[q][1];
            ch[q]  = (_Float16)x1v[q][2];
        }
        *(f16x4*)&sh_s[0][e_loc][u0] = s0h;
        *(f16x4*)&sh_s[1][e_loc][u0] = s1h;
        *(f16x4*)&sh_s[2][e_loc][u0] = x0h;
        *(f16x4*)&sh_s[3][e_loc][u0] = ah;
        *(f16x4*)&sh_s[4][e_loc][u0] = bh;
        *(f16x4*)&sh_s[5][e_loc][u0] = ch;
        if (pp == 0) sh_y[e_loc] = yv;
    }
    __syncthreads();

    // ---- phase 2: MFMA K-loop
    const int lane = t & 63, wv = t >> 6;
    const int m = lane & 15, quad = lane >> 4;
    const int e_loc = wv * 16 + m;
    const int qh = quad >> 1, ql = quad & 1;

    AF svh[6];
    #pragma unroll
    for (int b = 0; b < 6; ++b)
        svh[b].f = *(const f16x8*)&sh_s[b][e_loc][ql * 8];
    float hreg[8];
    #pragma unroll
    for (int kb = 0; kb < 8; ++kb) hreg[kb] = sh_h[e_loc][2 * kb + qh];

    f32x4 acc0  = {0.f, 0.f, 0.f, 0.f};
    f32x4 acc2  = {0.f, 0.f, 0.f, 0.f};
    f32x4 acc3a = {0.f, 0.f, 0.f, 0.f};
    f32x4 acc3b = {0.f, 0.f, 0.f, 0.f};
    f32x4 acc3c = {0.f, 0.f, 0.f, 0.f};

    for (int kb = 0; kb < 9; ++kb) {
        const f16x8 B0 = bfrag[(0 * 9 + kb) * 64 + lane];
        const f16x8 B1 = bfrag[(1 * 9 + kb) * 64 + lane];
        const f16x8 B2 = bfrag[(2 * 9 + kb) * 64 + lane];
        const f16x8 B3 = bfrag[(3 * 9 + kb) * 64 + lane];
        const float selF = (kb < 8) ? hreg[kb] : ((quad < 2) ? 1.0f : 0.0f);
        const _Float16 sh1 = (_Float16)selF;
        const f16x2 sel2 = (f16x2){sh1, sh1};
        AF A[6];
        #pragma unroll
        for (int b = 0; b < 6; ++b)
            #pragma unroll
            for (int p = 0; p < 4; ++p)
                A[b].h2[p] = sel2 * svh[b].h2[p];    // v_pk_mul_f16
        acc0  = __builtin_amdgcn_mfma_f32_16x16x32_f16(A[0].f, B0, acc0, 0, 0, 0);
        acc0  = __builtin_amdgcn_mfma_f32_16x16x32_f16(A[1].f, B1, acc0, 0, 0, 0);
        acc2  = __builtin_amdgcn_mfma_f32_16x16x32_f16(A[2].f, B2, acc2, 0, 0, 0);
        acc3a = __builtin_amdgcn_mfma_f32_16x16x32_f16(A[3].f, B3, acc3a, 0, 0, 0);
        acc3b = __builtin_amdgcn_mfma_f32_16x16x32_f16(A[4].f, B3, acc3b, 0, 0, 0);
        acc3c = __builtin_amdgcn_mfma_f32_16x16x32_f16(A[5].f, B3, acc3c, 0, 0, 0);
    }

    // ---- epilogue: contiguous f16 lane-chunked rows (2 KB per wave)
    #pragma unroll
    for (int r = 0; r < 4; ++r) {
        const int el = wv * 16 + quad * 4 + r;
        const float4 yv = sh_y[el];
        const float t2v = acc2[r];
        const float o0 = acc0[r];
        const float oa = yv.y * t2v + yv.x * acc3a[r];
        const float ob = yv.z * t2v + yv.x * acc3b[r];
        const float oc = yv.w * t2v + yv.x * acc3c[r];
        f16x4 pk = {(_Float16)o0, (_Float16)oa, (_Float16)ob, (_Float16)oc};
        *(f16x4*)(edge_out + (size_t)(ebase + el) * 64 + m * 4) = pk;
    }
}

// ================= gather (segment mean): indexed independent reads =================
// One wave per node. Lane l pre-loads pos[n*PAD+l] (coalesced); indices are
// broadcast via __shfl; the c row-reads are INDEPENDENT (no pointer chase),
// 4-way unrolled for memory-level parallelism.
__global__ __launch_bounds__(256) void k_gather(const _Float16* __restrict__ edge_out,
                                                const int* __restrict__ cnt,
                                                const int* __restrict__ pos,
                                                float* __restrict__ out) {
    const int t = threadIdx.x;
    const int lane = t & 63;
    const int n = blockIdx.x * 4 + (t >> 6);
    // in-row permutation: elem<16 -> row[elem*4]; elem=16+w*3+i -> row[w*4+1+i]
    int pe;
    if (lane < 16) pe = lane * 4;
    else { const int idx = lane - 16; const int w = idx / 3; pe = w * 4 + 1 + (idx - w * 3); }
    int c = cnt[n];
    if (c > PAD) c = PAD;
    const int p = (lane < c) ? pos[n * PAD + lane] : 0;   // coalesced 256 B
    float a0 = 0.f, a1 = 0.f, a2 = 0.f, a3 = 0.f;
    int j = 0;
    for (; j + 4 <= c; j += 4) {
        const int r0 = __shfl(p, j + 0);
        const int r1 = __shfl(p, j + 1);
        const int r2 = __shfl(p, j + 2);
        const int r3 = __shfl(p, j + 3);
        a0 += (float)edge_out[(size_t)r0 * 64 + pe];
        a1 += (float)edge_out[(size_t)r1 * 64 + pe];
        a2 += (float)edge_out[(size_t)r2 * 64 + pe];
        a3 += (float)edge_out[(size_t)r3 * 64 + pe];
    }
    for (; j < c; ++j) {
        const int r = __shfl(p, j);
        a0 += (float)edge_out[(size_t)r * 64 + pe];
    }
    const float acc = (a0 + a1) + (a2 + a3);
    out[n * 64 + lane] = acc / (c > 0 ? (float)c : 1.0f);
}

// ================= fallback path (round-1 atomic fp32, proven) =================
__global__ void k_zero_f(float* __restrict__ out, float* __restrict__ counts) {
    int i = blockIdx.x * 256 + threadIdx.x;
    if (i < OUT_ELEM) out[i] = 0.0f;
    if (i < NNODES)   counts[i] = 0.0f;
}

#define EPB 80
#define NE  8
__global__ __launch_bounds__(256) void k_conv_atomic(
        const float* __restrict__ node_attr,
        const int*   __restrict__ edge_index,
        const float* __restrict__ edge_attr,
        const float* __restrict__ edge_sh,
        const float* __restrict__ w1,
        const float* __restrict__ b1,
        const float* __restrict__ w2,
        const float* __restrict__ b2,
        float* __restrict__ out,
        float* __restrict__ counts)
{
    const int thr   = threadIdx.x;
    const int lane  = thr & 63;
    const int wv    = thr >> 6;
    const int u     = lane >> 2;
    const int wbase = (lane & 3) * 4;

    float4 w2r[16];
    #pragma unroll
    for (int k = 0; k < 16; ++k)
        w2r[k] = *(const float4*)(w2 + k * 1024 + thr * 4);
    const float4 b2r = *(const float4*)(b2 + thr * 4);

    __shared__ __align__(16) float sh_h[NE][16];
    __shared__ float sh_s0[NE][16];
    __shared__ float sh_s1[NE][16];
    __shared__ float sh_x0[NE][16];
    __shared__ float sh_x1[NE][16][3];
    __shared__ float sh_y0[NE];
    __shared__ float sh_y1[NE][3];
    __shared__ int   sh_dst[NE];

    const float alpha     = 0.17677669529663687f;
    const float inv_sqrt3 = 0.57735026918962576f;
    const int e0 = blockIdx.x * EPB;

    for (int batch = 0; batch < EPB / NE; ++batch) {
        const int ebase = e0 + batch * NE;
        if (thr < 128) {
            const int le = thr >> 4, k = thr & 15;
            const int e = ebase + le;
            float acc = b1[k];
            const float* ea = edge_attr + (size_t)e * 16;
            #pragma unroll
            for (int d = 0; d < 16; ++d) acc += ea[d] * w1[d * 16 + k];
            sh_h[le][k] = acc / (1.0f + __expf(-acc));
            if (k == 0) sh_dst[le] = edge_index[E_TOTAL + e];
        } else {
            const int le = (thr - 128) >> 4, uu = thr & 15;
            const int e = ebase + le;
            const int src = edge_index[e];
            const float y0  = edge_sh[e * 4 + 0];
            const float y1a = edge_sh[e * 4 + 1];
            const float y1b = edge_sh[e * 4 + 2];
            const float y1c = edge_sh[e * 4 + 3];
            const float* xp = node_attr + (size_t)src * 64;
            const float x0v = xp[uu];
            const float xa = xp[16 + uu * 3 + 0];
            const float xb = xp[16 + uu * 3 + 1];
            const float xc = xp[16 + uu * 3 + 2];
            sh_x0[le][uu] = x0v;
            sh_x1[le][uu][0] = xa; sh_x1[le][uu][1] = xb; sh_x1[le][uu][2] = xc;
            sh_s0[le][uu] = x0v * y0;
            sh_s1[le][uu] = inv_sqrt3 * (xa * y1a + xb * y1b + xc * y1c);
            if (uu == 0) {
                sh_y0[le] = y0;
                sh_y1[le][0] = y1a; sh_y1[le][1] = y1b; sh_y1[le][2] = y1c;
            }
        }
        __syncthreads();

        for (int le = 0; le < NE; ++le) {
            float W0 = b2r.x, W1 = b2r.y, W2c = b2r.z, W3c = b2r.w;
            const float4* hv = (const float4*)sh_h[le];
            #pragma unroll
            for (int kk = 0; kk < 4; ++kk) {
                const float4 h4 = hv[kk];
                const int kb = kk * 4;
                W0  += h4.x * w2r[kb + 0].x; W1  += h4.x * w2r[kb + 0].y;
                W2c += h4.x * w2r[kb + 0].z; W3c += h4.x * w2r[kb + 0].w;
                W0  += h4.y * w2r[kb + 1].x; W1  += h4.y * w2r[kb + 1].y;
                W2c += h4.y * w2r[kb + 1].z; W3c += h4.y * w2r[kb + 1].w;
                W0  += h4.z * w2r[kb + 2].x; W1  += h4.z * w2r[kb + 2].y;
                W2c += h4.z * w2r[kb + 2].z; W3c += h4.z * w2r[kb + 2].w;
                W0  += h4.w * w2r[kb + 3].x; W1  += h4.w * w2r[kb + 3].y;
                W2c += h4.w * w2r[kb + 3].z; W3c += h4.w * w2r[kb + 3].w;
            }
            const int dst = sh_dst[le];
            float* op = out + (size_t)dst * 64;
            if (wv == 0 || wv == 1) {
                const float s = (wv == 0) ? sh_s0[le][u] : sh_s1[le][u];
                float v0 = s * W0, v1 = s * W1, v2 = s * W2c, v3 = s * W3c;
                #pragma unroll
                for (int off = 4; off <= 32; off <<= 1) {
                    v0 += __shfl_xor(v0, off); v1 += __shfl_xor(v1, off);
                    v2 += __shfl_xor(v2, off); v3 += __shfl_xor(v3, off);
                }
                if (lane < 4) {
                    atomicAdd(op + wbase + 0, alpha * v0);
                    atomicAdd(op + wbase + 1, alpha * v1);
                    atomicAdd(op + wbase + 2, alpha * v2);
                    atomicAdd(op + wbase + 3, alpha * v3);
                    if (wv == 0 && lane == 0) atomicAdd(&counts[dst], 1.0f);
                }
            } else if (wv == 2) {
                const float s = sh_x0[le][u];
                float v0 = s * W0, v1 = s * W1, v2 = s * W2c, v3 = s * W3c;
                #pragma unroll
                for (int off = 4; off <= 32; off <<= 1) {
                    v0 += __shfl_xor(v0, off); v1 += __shfl_xor(v1, off);
                    v2 += __shfl_xor(v2, off); v3 += __shfl_xor(v3, off);
                }
                if (lane < 4) {
                    const float ya = alpha * sh_y1[le][0];
                    const float yb = alpha * sh_y1[le][1];
                    const float yc = alpha * sh_y1[le][2];
                    float vv[4] = {v0, v1, v2, v3};
                    #pragma unroll
                    for (int q = 0; q < 4; ++q) {
                        float* qp = op + 16 + (wbase + q) * 3;
                        atomicAdd(qp + 0, vv[q] * ya);
                        atomicAdd(qp + 1, vv[q] * yb);
                        atomicAdd(qp + 2, vv[q] * yc);
                    }
                }
            } else {
                const float ay0 = alpha * sh_y0[le];
                #pragma unroll
                for (int i = 0; i < 3; ++i) {
                    const float s = sh_x1[le][u][i];
                    float v0 = s * W0, v1 = s * W1, v2 = s * W2c, v3 = s * W3c;
                    #pragma unroll
                    for (int off = 4; off <= 32; off <<= 1) {
                        v0 += __shfl_xor(v0, off); v1 += __shfl_xor(v1, off);
                        v2 += __shfl_xor(v2, off); v3 += __shfl_xor(v3, off);
                    }
                    if (lane < 4) {
                        atomicAdd(op + 16 + (wbase + 0) * 3 + i, ay0 * v0);
                        atomicAdd(op + 16 + (wbase + 1) * 3 + i, ay0 * v1);
                        atomicAdd(op + 16 + (wbase + 2) * 3 + i, ay0 * v2);
                        atomicAdd(op + 16 + (wbase + 3) * 3 + i, ay0 * v3);
                    }
                }
            }
        }
        __syncthreads();
    }
}

__global__ void k_div(float* __restrict__ out, const float* __restrict__ counts) {
    int i = blockIdx.x * 256 + threadIdx.x;
    if (i < OUT_ELEM) {
        float c = counts[i >> 6];
        out[i] *= 1.0f / fmaxf(c, 1.0f);
    }
}

// ================= launch =================
extern "C" void kernel_launch(void* const* d_in, const int* in_sizes, int n_in,
                              void* d_out, int out_size, void* d_ws, size_t ws_size,
                              hipStream_t stream) {
    const float* node_attr  = (const float*)d_in[0];
    const int*   edge_index = (const int*)d_in[1];
    const float* edge_attr  = (const float*)d_in[2];
    const float* edge_sh    = (const float*)d_in[3];
    const float* w1         = (const float*)d_in[4];
    const float* b1         = (const float*)d_in[5];
    const float* w2         = (const float*)d_in[6];
    const float* b2         = (const float*)d_in[7];
    float* out = (float*)d_out;

    if (ws_size >= WS_NEEDED) {
        char* ws = (char*)d_ws;
        _Float16* edge_out = (_Float16*)ws;
        int*      cnt      = (int*)(ws + OFF_CNT);
        int*      pos      = (int*)(ws + OFF_POS);
        _Float16* bfrag    = (_Float16*)(ws + OFF_BFRAG);

        k_prep<<<(NNODES + 255) / 256, 256, 0, stream>>>(w2, b2, cnt, bfrag);
        k_conv<<<NTILE, 256, 0, stream>>>(
            node_attr, edge_index, edge_attr, edge_sh, w1, b1,
            (const f16x8*)bfrag, cnt, pos, edge_out);
        k_gather<<<NNODES / 4, 256, 0, stream>>>(edge_out, cnt, pos, out);
    } else {
        float* counts = (float*)d_ws;
        k_zero_f<<<(OUT_ELEM + 255) / 256, 256, 0, stream>>>(out, counts);
        k_conv_atomic<<<E_TOTAL / EPB, 256, 0, stream>>>(
            node_attr, edge_index, edge_attr, edge_sh, w1, b1, w2, b2, out, counts);
        k_div<<<(OUT_ELEM + 255) / 256, 256, 0, stream>>>(out, counts);
    }
}